// Round 11
// baseline (1039.870 us; speedup 1.0000x reference)
//
#include <hip/hip_runtime.h>
#include <hip/hip_bf16.h>
#include <stdint.h>

#define DEVI static __device__ __forceinline__

typedef __bf16 bf16x8 __attribute__((ext_vector_type(8)));
typedef float f32x4 __attribute__((ext_vector_type(4)));
typedef int   int4v __attribute__((ext_vector_type(4)));
typedef int   int2v __attribute__((ext_vector_type(2)));

DEVI float bf2f(uint16_t u){ uint32_t x = ((uint32_t)u) << 16; float f; __builtin_memcpy(&f, &x, 4); return f; }
DEVI uint16_t f2bf(float f){ uint32_t u; __builtin_memcpy(&u, &f, 4); uint32_t r = (u + 0x7FFFu + ((u >> 16) & 1u)) >> 16; return (uint16_t)r; }
DEVI float frcp(float x){ return __builtin_amdgcn_rcpf(x); }
DEVI float sigm(float x){ return frcp(1.f + __expf(-x)); }
DEVI float tanhfast(float x){ return 1.f - 2.f * frcp(1.f + __expf(2.f * x)); }
DEVI f32x4 mfma16(bf16x8 a, bf16x8 b, f32x4 c){ return __builtin_amdgcn_mfma_f32_16x16x32_bf16(a, b, c, 0, 0, 0); }

DEVI bf16x8 cvt8(const float* __restrict__ p){
    f32x4 a = *(const f32x4*)p, b = *(const f32x4*)(p + 4);
    union { bf16x8 v; uint16_t u[8]; } r;
    #pragma unroll
    for (int e = 0; e < 4; ++e) { r.u[e] = f2bf(a[e]); r.u[4 + e] = f2bf(b[e]); }
    return r.v;
}
DEVI int4v asint4(bf16x8 v){ int4v r; __builtin_memcpy(&r, &v, 16); return r; }

// raw barrier: lgkm drain only (vm ops — prefetch loads / Y stores — stay in flight)
DEVI void bar_lds(){
    asm volatile("s_waitcnt lgkmcnt(0)" ::: "memory");
    __builtin_amdgcn_s_barrier();
    __builtin_amdgcn_sched_barrier(0);
}

// XG layout (row-major, t-major rows): element (t, b, c) at (t*512 + b)*768 + c.

// ---------------------------------------------------------------------------
// Kernel 1: input projection (B*L,64)@(64,256) + bias + ReLU + LN -> Y bf16
// Y rows in t-major order: ri = t*512 + b. LDS-staged coalesced Y writes.
// grid 1024 x 256 thr.
// ---------------------------------------------------------------------------
__global__ __launch_bounds__(256) void k_inproj(
    const float* __restrict__ X, const float* __restrict__ W,
    const float* __restrict__ bias, const float* __restrict__ g,
    const float* __restrict__ beta, uint16_t* __restrict__ Y)
{
    __shared__ __align__(16) char As[64 * 128];
    __shared__ __align__(16) char Bs[256 * 128];
    __shared__ __align__(16) char Cs[64 * 520];   // staging, 520B stride (conflict-free)
    const int tid = threadIdx.x;
    const long rowbase = (long)blockIdx.x * 64;

    #pragma unroll
    for (int it = 0; it < 2; ++it) {
        int c = it * 256 + tid; int r = c >> 3, cc = c & 7;
        bf16x8 v = cvt8(X + (rowbase + r) * 64 + cc * 8);
        *(int4v*)(As + r * 128 + ((cc * 16) ^ ((r & 7) << 4))) = asint4(v);
    }
    #pragma unroll
    for (int it = 0; it < 8; ++it) {
        int c = it * 256 + tid; int r = c >> 3, cc = c & 7;
        bf16x8 v = cvt8(W + r * 64 + cc * 8);
        *(int4v*)(Bs + r * 128 + ((cc * 16) ^ ((r & 7) << 4))) = asint4(v);
    }
    __syncthreads();

    const int w = tid >> 6, l = tid & 63, lr = l & 15, lg = l >> 4;
    f32x4 acc[16];
    #pragma unroll
    for (int i = 0; i < 16; ++i) acc[i] = (f32x4){0.f, 0.f, 0.f, 0.f};
    const int arow = w * 16 + lr;
    #pragma unroll
    for (int ks = 0; ks < 2; ++ks) {
        bf16x8 a = *(bf16x8*)(As + arow * 128 + ((ks * 64 + lg * 16) ^ ((arow & 7) << 4)));
        #pragma unroll
        for (int tl = 0; tl < 16; ++tl) {
            int n = tl * 16 + lr;
            bf16x8 b = *(bf16x8*)(Bs + n * 128 + ((ks * 64 + lg * 16) ^ ((n & 7) << 4)));
            acc[tl] = mfma16(a, b, acc[tl]);
        }
    }
    float gv[16], bv[16], biasv[16];
    #pragma unroll
    for (int tl = 0; tl < 16; ++tl) {
        int col = tl * 16 + lr;
        gv[tl] = g[col]; bv[tl] = beta[col]; biasv[tl] = bias[col];
    }
    #pragma unroll
    for (int i = 0; i < 4; ++i) {
        float s = 0.f, sq = 0.f, v[16];
        #pragma unroll
        for (int tl = 0; tl < 16; ++tl) {
            float xv = acc[tl][i] + biasv[tl]; xv = fmaxf(xv, 0.f);
            v[tl] = xv; s += xv; sq += xv * xv;
        }
        #pragma unroll
        for (int d = 1; d < 16; d <<= 1) { s += __shfl_xor(s, d); sq += __shfl_xor(sq, d); }
        float mean = s * (1.f / 256.f);
        float var  = sq * (1.f / 256.f) - mean * mean;
        float sc   = rsqrtf(var + 1e-5f);
        int rl = w * 16 + lg * 4 + i;
        #pragma unroll
        for (int tl = 0; tl < 16; ++tl)
            *(uint16_t*)(Cs + rl * 520 + (tl * 16 + lr) * 2) =
                f2bf((v[tl] - mean) * sc * gv[tl] + bv[tl]);
    }
    __syncthreads();
    #pragma unroll
    for (int it = 0; it < 16; ++it) {
        int idx = it * 256 + tid;
        int rl = idx >> 6, ch = idx & 63;
        long rg = rowbase + rl;
        long ri = ((rg & 127) << 9) + (rg >> 7);      // t-major
        *(int2v*)(Y + ri * 256 + ch * 4) = *(int2v*)(Cs + rl * 520 + ch * 8);
    }
}

// ---------------------------------------------------------------------------
// Kernel 2: input-gate GEMM, persistent-N. Block owns a 192-col strip (B in
// LDS once), loops 8 x 128-row tiles; A-frags loaded global->reg per tile.
// Output tile staged in LDS (400B row stride), then written as contiguous
// 16B/lane dwordx4 spans — eliminates partial-sector RMW on XG stores.
// grid (64, 4) x 512 thr.
// ---------------------------------------------------------------------------
template<int KIN, bool ZBUILD>
__global__ __launch_bounds__(512) void k_xg(
    const uint16_t* __restrict__ A, const float* __restrict__ W,
    const float* __restrict__ bias, uint16_t* __restrict__ XG,
    const float* __restrict__ zbuf, const float* __restrict__ noise)
{
    constexpr int KB = KIN * 2;           // bf16 row bytes
    constexpr int KS = KIN / 32;          // mfma k-steps
    __shared__ __align__(16) char Bs[192 * KB];
    __shared__ __align__(16) char Cs[128 * 400];   // out-tile staging
    const int tid = threadIdx.x;
    const int nb = blockIdx.y;

    constexpr int CPR = KIN / 8;          // 8-f32 chunks per row
    for (int c = tid; c < 192 * CPR; c += 512) {
        int r = c / CPR, cc = c % CPR;
        bf16x8 v = cvt8(W + (long)(nb * 192 + r) * KIN + cc * 8);
        *(int4v*)(Bs + r * KB + ((cc * 16) ^ ((r & 7) << 4))) = asint4(v);
    }
    __syncthreads();

    const int w = tid >> 6, l = tid & 63, lr = l & 15, lg = l >> 4;
    float bvs[12];
    #pragma unroll
    for (int tl = 0; tl < 12; ++tl) bvs[tl] = bias[nb * 192 + tl * 16 + lr];

    for (int rt = 0; rt < 8; ++rt) {
        const long rowb = (long)blockIdx.x * 1024 + rt * 128;
        const long ria  = rowb + w * 16 + lr;
        bf16x8 a[KS];
        if constexpr (!ZBUILD) {
            #pragma unroll
            for (int ks = 0; ks < KS; ++ks)
                a[ks] = *(const bf16x8*)(A + ria * KIN + ks * 32 + lg * 8);
        } else {
            int b = (int)(ria & 511), t = (int)(ria >> 9);
            #pragma unroll
            for (int ks = 0; ks < KS; ++ks) {
                int k0 = ks * 32 + lg * 8;
                const float* zr = zbuf + b * 64 + k0;
                const float* nr = noise + ((long)b * 128 + t) * 64 + k0;
                f32x4 z0 = *(const f32x4*)zr, z1 = *(const f32x4*)(zr + 4);
                f32x4 n0 = *(const f32x4*)nr, n1 = *(const f32x4*)(nr + 4);
                union { bf16x8 v; uint16_t u[8]; } un;
                #pragma unroll
                for (int e = 0; e < 4; ++e) {
                    un.u[e]     = f2bf(z0[e] + 0.05f * n0[e]);
                    un.u[4 + e] = f2bf(z1[e] + 0.05f * n1[e]);
                }
                a[ks] = un.v;
            }
        }
        f32x4 acc[12];
        #pragma unroll
        for (int i = 0; i < 12; ++i) acc[i] = (f32x4){0.f, 0.f, 0.f, 0.f};
        #pragma unroll
        for (int ks = 0; ks < KS; ++ks) {
            #pragma unroll
            for (int tl = 0; tl < 12; ++tl) {
                int n = tl * 16 + lr;
                bf16x8 b = *(bf16x8*)(Bs + n * KB + ((ks * 64 + lg * 16) ^ ((n & 7) << 4)));
                acc[tl] = mfma16(a[ks], b, acc[tl]);
            }
        }
        // stage output tile in LDS: row = w*16+lg*4+i (0..127), col = tl*16+lr
        #pragma unroll
        for (int tl = 0; tl < 12; ++tl) {
            #pragma unroll
            for (int i = 0; i < 4; ++i)
                *(uint16_t*)(Cs + (w * 16 + lg * 4 + i) * 400 + (tl * 16 + lr) * 2) =
                    f2bf(acc[tl][i] + bvs[tl]);
        }
        __syncthreads();
        // write out: 128 rows x 384B strip, 16B/lane contiguous (3072 chunks)
        #pragma unroll
        for (int it = 0; it < 6; ++it) {
            int idx = it * 512 + tid;
            int row = idx / 24, ch = idx % 24;
            *(int4v*)(XG + (rowb + row) * 768 + nb * 192 + ch * 8) =
                *(int4v*)(Cs + row * 400 + ch * 16);
        }
        __syncthreads();   // Cs free for next rt
    }
}

// ---------------------------------------------------------------------------
// Kernel 3: persistent GRU. grid = 256 blocks x 512 thr (8 waves), 2 rows/block.
// Whh k[0,224) in VGPRs (wf[6][7]); k[224,256) in LDS (72B stride, conflict-
// free) loaded EARLY each step into wt[6] so the tail read latency hides under
// the MFMA chain. h as 2x512B in LDS, disjoint-bank swizzle (row1 XOR 64B).
// Y[t] = h(t+1) already lives in Abuf: wave 0 alone stores it one step
// deferred as coalesced 16B/lane spans (kills 32B-segment RMW + per-lane
// addressing in the other 7 waves). Incremental xga pointers.
// ---------------------------------------------------------------------------
__global__ __launch_bounds__(512) void k_gru(
    const uint16_t* __restrict__ XG, const float* __restrict__ Whh,
    const float* __restrict__ bhh, uint16_t* __restrict__ Y,
    float* __restrict__ hlast)
{
    constexpr int L = 128;
    __shared__ __align__(16) char Abuf[2][2 * 512];   // h bf16, 2 rows, swizzled
    __shared__ __align__(16) char Wt[768 * 72 + 8];   // Whh k-tail [224,256), 72B stride
    const int tid = threadIdx.x;
    const int w = tid >> 6, l = tid & 63, lr = l & 15, lg = l >> 4;
    const int rowg0 = blockIdx.x * 2;

    ((uint32_t*)Abuf)[tid] = 0;                        // zero both h buffers (512 words)

    #pragma unroll
    for (int it = 0; it < 6; ++it) {                   // stage Wt: 768 rows x 4 chunks
        int c = it * 512 + tid; int r = c >> 2, cc = c & 3;
        bf16x8 v = cvt8(Whh + (long)r * 256 + 224 + cc * 8);
        *(int4v*)(Wt + r * 72 + cc * 16) = asint4(v);
    }

    int gb[6];
    #pragma unroll
    for (int tl = 0; tl < 6; ++tl) gb[tl] = (tl >> 1) * 256 + w * 32 + (tl & 1) * 16;
    bf16x8 wf[6][7];                                   // K 0..223 register-resident
    #pragma unroll
    for (int tl = 0; tl < 6; ++tl)
        #pragma unroll
        for (int ks = 0; ks < 7; ++ks)
            wf[tl][ks] = cvt8(Whh + (long)(gb[tl] + lr) * 256 + ks * 32 + lg * 8);
    int wtaddr[6];                                     // precomputed Wt byte addrs
    #pragma unroll
    for (int tl = 0; tl < 6; ++tl) wtaddr[tl] = (gb[tl] + lr) * 72 + lg * 16;

    const int i_  = lg & 1;                            // local batch row 0/1
    const int sub = (lg >> 1) & 1;
    const int col = w * 32 + sub * 16 + lr;            // h column 0..255
    const float bR = bhh[col], bZ = bhh[256 + col], bN = bhh[512 + col];
    const long rowl = rowg0 + i_;                      // global batch row
    // disjoint-bank h layout: row i_ region at i_*512, chunk base XOR (i_<<6)
    const int wrbyte = i_ * 512 + ((((col * 2) & ~15) ^ (i_ << 6)) | ((col * 2) & 15));

    const uint16_t* xgp = XG + rowl * 768;             // incremental xg pointer
    uint16_t xga0 = xgp[col];
    uint16_t xga1 = xgp[256 + col];
    uint16_t xga2 = xgp[512 + col];
    xgp += 393216;

    // wave-0 deferred Y store: lane l -> row i2=l>>5, chunk c8=l&31 (16B)
    const int yi2 = l >> 5, yc8 = l & 31;
    const int ylds = yi2 * 512 + ((yc8 * 16) ^ (yi2 << 6));
    uint16_t* yp = (Y != nullptr) ? (Y + ((long)rowg0 + yi2) * 256 + yc8 * 8) : nullptr;

    float h = 0.f;
    const int arow = lr & 1;                           // broadcast A row
    __syncthreads();

    for (int t = 0; t < L; ++t) {
        const int p = t & 1;
        const char* ab = Abuf[p];

        // wave 0: store Y[t-1] (= Abuf[p]) as coalesced 512B row spans
        if (w == 0 && t > 0 && yp != nullptr) {
            int4v yv = *(int4v*)(ab + ylds);
            *(int4v*)(yp + (long)(t - 1) * 131072) = yv;
        }

        f32x4 acc[6];
        #pragma unroll
        for (int i = 0; i < 6; ++i) acc[i] = (f32x4){0.f, 0.f, 0.f, 0.f};

        bf16x8 acur = *(bf16x8*)(ab + arow * 512 + ((lg * 16) ^ (arow << 6)));
        bf16x8 wt[6];                                  // issue Wt tail reads EARLY
        #pragma unroll
        for (int tl = 0; tl < 6; ++tl) wt[tl] = *(bf16x8*)(Wt + wtaddr[tl]);

        __builtin_amdgcn_s_setprio(1);
        #pragma unroll
        for (int ks = 0; ks < 8; ++ks) {
            bf16x8 anx;
            if (ks < 7)
                anx = *(bf16x8*)(ab + arow * 512 + (((ks + 1) * 64 + lg * 16) ^ (arow << 6)));
            if (ks < 7) {
                #pragma unroll
                for (int tl = 0; tl < 6; ++tl) acc[tl] = mfma16(acur, wf[tl][ks], acc[tl]);
            } else {
                #pragma unroll
                for (int tl = 0; tl < 6; ++tl) acc[tl] = mfma16(acur, wt[tl], acc[tl]);
            }
            acur = anx;
        }
        __builtin_amdgcn_s_setprio(0);

        float xr = bf2f(xga0), xz = bf2f(xga1), xn = bf2f(xga2);
        if (t + 1 < L) {                               // prefetch xg(t+1) early
            xga0 = xgp[col]; xga1 = xgp[256 + col]; xga2 = xgp[512 + col];
            xgp += 393216;
        }
        float pre0, pre1, pre2;
        {
            float a0 = i_ ? acc[0][1] : acc[0][0];
            float a1 = i_ ? acc[1][1] : acc[1][0];
            pre0 = sub ? a1 : a0;
            float b0 = i_ ? acc[2][1] : acc[2][0];
            float b1 = i_ ? acc[3][1] : acc[3][0];
            pre1 = sub ? b1 : b0;
            float c0 = i_ ? acc[4][1] : acc[4][0];
            float c1 = i_ ? acc[5][1] : acc[5][0];
            pre2 = sub ? c1 : c0;
        }
        float R = sigm(xr + pre0 + bR);
        float Z = sigm(xz + pre1 + bZ);
        float N = tanhfast(xn + R * (pre2 + bN));
        h = N + Z * (h - N);
        *(uint16_t*)(Abuf[p ^ 1] + wrbyte) = f2bf(h);

        bar_lds();
    }
    // final Y row: Y[L-1] = Abuf[L&1] (= Abuf[0])
    if (w == 0 && yp != nullptr) {
        int4v yv = *(int4v*)(Abuf[L & 1] + ylds);
        *(int4v*)(yp + (long)(L - 1) * 131072) = yv;
    }
    if (hlast) hlast[rowl * 256 + col] = h;
}

// ---------------------------------------------------------------------------
// Kernel 4: mu / log_var / z.  grid = 256 blocks x 256 thr, 2 rows/block.
// ---------------------------------------------------------------------------
__global__ __launch_bounds__(256) void k_z(
    const float* __restrict__ hlast, const float* __restrict__ muW,
    const float* __restrict__ mub, const float* __restrict__ lvW,
    const float* __restrict__ lvb, const float* __restrict__ eps,
    float* __restrict__ mu_out, float* __restrict__ lv_out,
    float* __restrict__ zout)
{
    __shared__ float hrow[2][256];
    __shared__ float res[2][128];
    const int tid = threadIdx.x;
    const long row0 = (long)blockIdx.x * 2;
    for (int i = tid; i < 512; i += 256) ((float*)hrow)[i] = hlast[row0 * 256 + i];
    __syncthreads();
    const int lrr = tid >> 7, c = tid & 127;
    const float* Wr = (c < 64 ? muW : lvW) + (long)(c & 63) * 256;
    float acc = (c < 64) ? mub[c] : lvb[c & 63];
    const float* hr = hrow[lrr];
    #pragma unroll 8
    for (int k = 0; k < 256; k += 4) {
        f32x4 wv = *(const f32x4*)(Wr + k);
        #pragma unroll
        for (int e = 0; e < 4; ++e) acc += hr[k + e] * wv[e];
    }
    res[lrr][c] = acc;
    long row = row0 + lrr;
    if (c < 64) mu_out[row * 64 + c] = acc;
    else        lv_out[row * 64 + (c & 63)] = acc;
    __syncthreads();
    if (c < 64) {
        float m = res[lrr][c], lv = res[lrr][64 + c];
        zout[row * 64 + c] = m + eps[row * 64 + c] * __expf(0.5f * lv);
    }
}

// ---------------------------------------------------------------------------
// Kernel 5: post proj + ReLU + LN, then output proj + tanh -> x_hat (f32).
// D1 rows are t-major ri; x_hat written b-major. grid 1024 x 256 thr.
// ---------------------------------------------------------------------------
__global__ __launch_bounds__(256) void k_post(
    const uint16_t* __restrict__ D1, const float* __restrict__ pW,
    const float* __restrict__ pb, const float* __restrict__ pg,
    const float* __restrict__ pbeta, const float* __restrict__ oW,
    const float* __restrict__ ob, float* __restrict__ xhat)
{
    __shared__ __align__(16) char Bs[256 * 512];
    const int tid = threadIdx.x;
    const long rowbase = (long)blockIdx.x * 64;
    #pragma unroll
    for (int it = 0; it < 32; ++it) {
        int c = it * 256 + tid; int r = c >> 5, cc = c & 31;
        bf16x8 v = cvt8(pW + r * 256 + cc * 8);
        *(int4v*)(Bs + r * 512 + ((cc * 16) ^ ((r & 7) << 4))) = asint4(v);
    }
    __syncthreads();
    const int w = tid >> 6, l = tid & 63, lr = l & 15, lg = l >> 4;
    const long arow = rowbase + w * 16 + lr;
    bf16x8 af[8];
    #pragma unroll
    for (int ks = 0; ks < 8; ++ks) af[ks] = *(const bf16x8*)(D1 + arow * 256 + ks * 32 + lg * 8);
    f32x4 acc[16];
    #pragma unroll
    for (int i = 0; i < 16; ++i) acc[i] = (f32x4){0.f, 0.f, 0.f, 0.f};
    #pragma unroll
    for (int ks = 0; ks < 8; ++ks) {
        #pragma unroll
        for (int tl = 0; tl < 16; ++tl) {
            int n = tl * 16 + lr;
            bf16x8 b = *(bf16x8*)(Bs + n * 512 + ((ks * 64 + lg * 16) ^ ((n & 7) << 4)));
            acc[tl] = mfma16(af[ks], b, acc[tl]);
        }
    }
    float gv[16], bv[16], biasv[16];
    #pragma unroll
    for (int tl = 0; tl < 16; ++tl) {
        int col = tl * 16 + lr;
        gv[tl] = pg[col]; bv[tl] = pbeta[col]; biasv[tl] = pb[col];
    }
    uint16_t dl[16][4];
    #pragma unroll
    for (int i = 0; i < 4; ++i) {
        float s = 0.f, sq = 0.f, v[16];
        #pragma unroll
        for (int tl = 0; tl < 16; ++tl) {
            float xv = acc[tl][i] + biasv[tl]; xv = fmaxf(xv, 0.f);
            v[tl] = xv; s += xv; sq += xv * xv;
        }
        #pragma unroll
        for (int d = 1; d < 16; d <<= 1) { s += __shfl_xor(s, d); sq += __shfl_xor(sq, d); }
        float mean = s * (1.f / 256.f);
        float var  = sq * (1.f / 256.f) - mean * mean;
        float sc   = rsqrtf(var + 1e-5f);
        #pragma unroll
        for (int tl = 0; tl < 16; ++tl)
            dl[tl][i] = f2bf((v[tl] - mean) * sc * gv[tl] + bv[tl]);
    }
    __syncthreads();
    #pragma unroll
    for (int tl = 0; tl < 16; ++tl) {
        int col = tl * 16 + lr;
        #pragma unroll
        for (int i = 0; i < 4; ++i) {
            int row = w * 16 + lg * 4 + i;
            *(uint16_t*)(Bs + row * 512 + (((col * 2) & ~15) ^ ((row & 7) << 4)) + ((col * 2) & 15)) = dl[tl][i];
        }
    }
    __syncthreads();
    const int ar2 = w * 16 + lr;
    f32x4 acc2[4];
    #pragma unroll
    for (int i = 0; i < 4; ++i) acc2[i] = (f32x4){0.f, 0.f, 0.f, 0.f};
    #pragma unroll
    for (int ks = 0; ks < 8; ++ks) {
        bf16x8 a = *(bf16x8*)(Bs + ar2 * 512 + ((ks * 64 + lg * 16) ^ ((ar2 & 7) << 4)));
        #pragma unroll
        for (int tl = 0; tl < 4; ++tl) {
            int n = tl * 16 + lr;
            bf16x8 b = cvt8(oW + n * 256 + ks * 32 + lg * 8);
            acc2[tl] = mfma16(a, b, acc2[tl]);
        }
    }
    #pragma unroll
    for (int tl = 0; tl < 4; ++tl) {
        int col = tl * 16 + lr;
        float bo = ob[col];
        #pragma unroll
        for (int i = 0; i < 4; ++i) {
            long ri = rowbase + w * 16 + lg * 4 + i;
            long b = ri & 511, t = ri >> 9;
            xhat[(b * 128 + t) * 64 + col] = tanhfast(acc2[tl][i] + bo);
        }
    }
}

// ---------------------------------------------------------------------------
extern "C" void kernel_launch(void* const* d_in, const int* in_sizes, int n_in,
                              void* d_out, int out_size, void* d_ws, size_t ws_size,
                              hipStream_t stream)
{
    (void)in_sizes; (void)n_in; (void)out_size; (void)ws_size;
    const float* x     = (const float*)d_in[0];
    const float* eps   = (const float*)d_in[1];
    const float* dnz   = (const float*)d_in[2];
    const float* in_W  = (const float*)d_in[3];
    const float* in_b  = (const float*)d_in[4];
    const float* in_g  = (const float*)d_in[5];
    const float* in_be = (const float*)d_in[6];
    const float* eW0i  = (const float*)d_in[7];
    const float* eW0h  = (const float*)d_in[8];
    const float* eb0i  = (const float*)d_in[9];
    const float* eb0h  = (const float*)d_in[10];
    const float* eW1i  = (const float*)d_in[11];
    const float* eW1h  = (const float*)d_in[12];
    const float* eb1i  = (const float*)d_in[13];
    const float* eb1h  = (const float*)d_in[14];
    const float* mu_W  = (const float*)d_in[15];
    const float* mu_b  = (const float*)d_in[16];
    const float* lv_W  = (const float*)d_in[17];
    const float* lv_b  = (const float*)d_in[18];
    const float* dW0i  = (const float*)d_in[19];
    const float* dW0h  = (const float*)d_in[20];
    const float* db0i  = (const float*)d_in[21];
    const float* db0h  = (const float*)d_in[22];
    const float* dW1i  = (const float*)d_in[23];
    const float* dW1h  = (const float*)d_in[24];
    const float* db1i  = (const float*)d_in[25];
    const float* db1h  = (const float*)d_in[26];
    const float* postW = (const float*)d_in[27];
    const float* postb = (const float*)d_in[28];
    const float* postg = (const float*)d_in[29];
    const float* postbe= (const float*)d_in[30];
    const float* outW  = (const float*)d_in[31];
    const float* outb  = (const float*)d_in[32];

    char* ws = (char*)d_ws;
    uint16_t* XG   = (uint16_t*)(ws);                 // 65536*768*2 = 100663296 B
    uint16_t* YA   = (uint16_t*)(ws + 100663296);     // 33554432 B
    uint16_t* YB   = (uint16_t*)(ws + 134217728);     // 33554432 B
    float*    hlast= (float*)   (ws + 167772160);     // 524288 B
    float*    zbuf = (float*)   (ws + 168296448);     // 131072 B

    float* out    = (float*)d_out;
    float* mu_out = out + 4194304;
    float* lv_out = out + 4194304 + 32768;

    dim3 b256(256), b512(512);
    dim3 gxg(64, 4);

    k_inproj<<<1024, b256, 0, stream>>>(x, in_W, in_b, in_g, in_be, YA);
    k_xg<256,false><<<gxg, b512, 0, stream>>>(YA, eW0i, eb0i, XG, nullptr, nullptr);
    k_gru<<<256, b512, 0, stream>>>(XG, eW0h, eb0h, YB, nullptr);
    k_xg<256,false><<<gxg, b512, 0, stream>>>(YB, eW1i, eb1i, XG, nullptr, nullptr);
    k_gru<<<256, b512, 0, stream>>>(XG, eW1h, eb1h, nullptr, hlast);
    k_z<<<256, b256, 0, stream>>>(hlast, mu_W, mu_b, lv_W, lv_b, eps, mu_out, lv_out, zbuf);
    k_xg<64,true><<<gxg, b512, 0, stream>>>(nullptr, dW0i, db0i, XG, zbuf, dnz);
    k_gru<<<256, b512, 0, stream>>>(XG, dW0h, db0h, YA, nullptr);
    k_xg<256,false><<<gxg, b512, 0, stream>>>(YA, dW1i, db1i, XG, nullptr, nullptr);
    k_gru<<<256, b512, 0, stream>>>(XG, dW1h, db1h, YB, nullptr);
    k_post<<<1024, b256, 0, stream>>>(YB, postW, postb, postg, postbe, outW, outb, out);
}

// Round 12
// 957.782 us; speedup vs baseline: 1.0857x; 1.0857x over previous
//
#include <hip/hip_runtime.h>
#include <hip/hip_bf16.h>
#include <stdint.h>

#define DEVI static __device__ __forceinline__

typedef __bf16 bf16x8 __attribute__((ext_vector_type(8)));
typedef float f32x4 __attribute__((ext_vector_type(4)));
typedef int   int4v __attribute__((ext_vector_type(4)));
typedef int   int2v __attribute__((ext_vector_type(2)));

DEVI float bf2f(uint16_t u){ uint32_t x = ((uint32_t)u) << 16; float f; __builtin_memcpy(&f, &x, 4); return f; }
DEVI uint16_t f2bf(float f){ uint32_t u; __builtin_memcpy(&u, &f, 4); uint32_t r = (u + 0x7FFFu + ((u >> 16) & 1u)) >> 16; return (uint16_t)r; }
DEVI float frcp(float x){ return __builtin_amdgcn_rcpf(x); }
DEVI float sigm(float x){ return frcp(1.f + __expf(-x)); }
DEVI float tanhfast(float x){ return 1.f - 2.f * frcp(1.f + __expf(2.f * x)); }
DEVI f32x4 mfma16(bf16x8 a, bf16x8 b, f32x4 c){ return __builtin_amdgcn_mfma_f32_16x16x32_bf16(a, b, c, 0, 0, 0); }

DEVI bf16x8 cvt8(const float* __restrict__ p){
    f32x4 a = *(const f32x4*)p, b = *(const f32x4*)(p + 4);
    union { bf16x8 v; uint16_t u[8]; } r;
    #pragma unroll
    for (int e = 0; e < 4; ++e) { r.u[e] = f2bf(a[e]); r.u[4 + e] = f2bf(b[e]); }
    return r.v;
}
DEVI int4v asint4(bf16x8 v){ int4v r; __builtin_memcpy(&r, &v, 16); return r; }

// raw barrier: lgkm drain only (vm ops — prefetch loads / Y stores — stay in flight)
DEVI void bar_lds(){
    asm volatile("s_waitcnt lgkmcnt(0)" ::: "memory");
    __builtin_amdgcn_s_barrier();
    __builtin_amdgcn_sched_barrier(0);
}

// XG layout (row-major, t-major rows): element (t, b, c) at (t*512 + b)*768 + c.

// ---------------------------------------------------------------------------
// Kernel 1: input projection (B*L,64)@(64,256) + bias + ReLU + LN -> Y bf16
// Y rows in t-major order: ri = t*512 + b. LDS-staged coalesced Y writes.
// grid 1024 x 256 thr.
// ---------------------------------------------------------------------------
__global__ __launch_bounds__(256) void k_inproj(
    const float* __restrict__ X, const float* __restrict__ W,
    const float* __restrict__ bias, const float* __restrict__ g,
    const float* __restrict__ beta, uint16_t* __restrict__ Y)
{
    __shared__ __align__(16) char As[64 * 128];
    __shared__ __align__(16) char Bs[256 * 128];
    __shared__ __align__(16) char Cs[64 * 520];   // staging, 520B stride (conflict-free)
    const int tid = threadIdx.x;
    const long rowbase = (long)blockIdx.x * 64;

    #pragma unroll
    for (int it = 0; it < 2; ++it) {
        int c = it * 256 + tid; int r = c >> 3, cc = c & 7;
        bf16x8 v = cvt8(X + (rowbase + r) * 64 + cc * 8);
        *(int4v*)(As + r * 128 + ((cc * 16) ^ ((r & 7) << 4))) = asint4(v);
    }
    #pragma unroll
    for (int it = 0; it < 8; ++it) {
        int c = it * 256 + tid; int r = c >> 3, cc = c & 7;
        bf16x8 v = cvt8(W + r * 64 + cc * 8);
        *(int4v*)(Bs + r * 128 + ((cc * 16) ^ ((r & 7) << 4))) = asint4(v);
    }
    __syncthreads();

    const int w = tid >> 6, l = tid & 63, lr = l & 15, lg = l >> 4;
    f32x4 acc[16];
    #pragma unroll
    for (int i = 0; i < 16; ++i) acc[i] = (f32x4){0.f, 0.f, 0.f, 0.f};
    const int arow = w * 16 + lr;
    #pragma unroll
    for (int ks = 0; ks < 2; ++ks) {
        bf16x8 a = *(bf16x8*)(As + arow * 128 + ((ks * 64 + lg * 16) ^ ((arow & 7) << 4)));
        #pragma unroll
        for (int tl = 0; tl < 16; ++tl) {
            int n = tl * 16 + lr;
            bf16x8 b = *(bf16x8*)(Bs + n * 128 + ((ks * 64 + lg * 16) ^ ((n & 7) << 4)));
            acc[tl] = mfma16(a, b, acc[tl]);
        }
    }
    float gv[16], bv[16], biasv[16];
    #pragma unroll
    for (int tl = 0; tl < 16; ++tl) {
        int col = tl * 16 + lr;
        gv[tl] = g[col]; bv[tl] = beta[col]; biasv[tl] = bias[col];
    }
    #pragma unroll
    for (int i = 0; i < 4; ++i) {
        float s = 0.f, sq = 0.f, v[16];
        #pragma unroll
        for (int tl = 0; tl < 16; ++tl) {
            float xv = acc[tl][i] + biasv[tl]; xv = fmaxf(xv, 0.f);
            v[tl] = xv; s += xv; sq += xv * xv;
        }
        #pragma unroll
        for (int d = 1; d < 16; d <<= 1) { s += __shfl_xor(s, d); sq += __shfl_xor(sq, d); }
        float mean = s * (1.f / 256.f);
        float var  = sq * (1.f / 256.f) - mean * mean;
        float sc   = rsqrtf(var + 1e-5f);
        int rl = w * 16 + lg * 4 + i;
        #pragma unroll
        for (int tl = 0; tl < 16; ++tl)
            *(uint16_t*)(Cs + rl * 520 + (tl * 16 + lr) * 2) =
                f2bf((v[tl] - mean) * sc * gv[tl] + bv[tl]);
    }
    __syncthreads();
    #pragma unroll
    for (int it = 0; it < 16; ++it) {
        int idx = it * 256 + tid;
        int rl = idx >> 6, ch = idx & 63;
        long rg = rowbase + rl;
        long ri = ((rg & 127) << 9) + (rg >> 7);      // t-major
        *(int2v*)(Y + ri * 256 + ch * 4) = *(int2v*)(Cs + rl * 520 + ch * 8);
    }
}

// ---------------------------------------------------------------------------
// Kernel 2: input-gate GEMM, persistent-N. Block owns a 192-col strip (B in
// LDS once), loops 8 x 128-row tiles; A-frags loaded global->reg per tile.
// Output tile staged in LDS (400B row stride), then written as contiguous
// 16B/lane dwordx4 spans — eliminates partial-sector RMW on XG stores.
// grid (64, 4) x 512 thr.
// ---------------------------------------------------------------------------
template<int KIN, bool ZBUILD>
__global__ __launch_bounds__(512) void k_xg(
    const uint16_t* __restrict__ A, const float* __restrict__ W,
    const float* __restrict__ bias, uint16_t* __restrict__ XG,
    const float* __restrict__ zbuf, const float* __restrict__ noise)
{
    constexpr int KB = KIN * 2;           // bf16 row bytes
    constexpr int KS = KIN / 32;          // mfma k-steps
    __shared__ __align__(16) char Bs[192 * KB];
    __shared__ __align__(16) char Cs[128 * 400];   // out-tile staging
    const int tid = threadIdx.x;
    const int nb = blockIdx.y;

    constexpr int CPR = KIN / 8;          // 8-f32 chunks per row
    for (int c = tid; c < 192 * CPR; c += 512) {
        int r = c / CPR, cc = c % CPR;
        bf16x8 v = cvt8(W + (long)(nb * 192 + r) * KIN + cc * 8);
        *(int4v*)(Bs + r * KB + ((cc * 16) ^ ((r & 7) << 4))) = asint4(v);
    }
    __syncthreads();

    const int w = tid >> 6, l = tid & 63, lr = l & 15, lg = l >> 4;
    float bvs[12];
    #pragma unroll
    for (int tl = 0; tl < 12; ++tl) bvs[tl] = bias[nb * 192 + tl * 16 + lr];

    for (int rt = 0; rt < 8; ++rt) {
        const long rowb = (long)blockIdx.x * 1024 + rt * 128;
        const long ria  = rowb + w * 16 + lr;
        bf16x8 a[KS];
        if constexpr (!ZBUILD) {
            #pragma unroll
            for (int ks = 0; ks < KS; ++ks)
                a[ks] = *(const bf16x8*)(A + ria * KIN + ks * 32 + lg * 8);
        } else {
            int b = (int)(ria & 511), t = (int)(ria >> 9);
            #pragma unroll
            for (int ks = 0; ks < KS; ++ks) {
                int k0 = ks * 32 + lg * 8;
                const float* zr = zbuf + b * 64 + k0;
                const float* nr = noise + ((long)b * 128 + t) * 64 + k0;
                f32x4 z0 = *(const f32x4*)zr, z1 = *(const f32x4*)(zr + 4);
                f32x4 n0 = *(const f32x4*)nr, n1 = *(const f32x4*)(nr + 4);
                union { bf16x8 v; uint16_t u[8]; } un;
                #pragma unroll
                for (int e = 0; e < 4; ++e) {
                    un.u[e]     = f2bf(z0[e] + 0.05f * n0[e]);
                    un.u[4 + e] = f2bf(z1[e] + 0.05f * n1[e]);
                }
                a[ks] = un.v;
            }
        }
        f32x4 acc[12];
        #pragma unroll
        for (int i = 0; i < 12; ++i) acc[i] = (f32x4){0.f, 0.f, 0.f, 0.f};
        #pragma unroll
        for (int ks = 0; ks < KS; ++ks) {
            #pragma unroll
            for (int tl = 0; tl < 12; ++tl) {
                int n = tl * 16 + lr;
                bf16x8 b = *(bf16x8*)(Bs + n * KB + ((ks * 64 + lg * 16) ^ ((n & 7) << 4)));
                acc[tl] = mfma16(a[ks], b, acc[tl]);
            }
        }
        // stage output tile in LDS: row = w*16+lg*4+i (0..127), col = tl*16+lr
        #pragma unroll
        for (int tl = 0; tl < 12; ++tl) {
            #pragma unroll
            for (int i = 0; i < 4; ++i)
                *(uint16_t*)(Cs + (w * 16 + lg * 4 + i) * 400 + (tl * 16 + lr) * 2) =
                    f2bf(acc[tl][i] + bvs[tl]);
        }
        __syncthreads();
        // write out: 128 rows x 384B strip, 16B/lane contiguous (3072 chunks)
        #pragma unroll
        for (int it = 0; it < 6; ++it) {
            int idx = it * 512 + tid;
            int row = idx / 24, ch = idx % 24;
            *(int4v*)(XG + (rowb + row) * 768 + nb * 192 + ch * 8) =
                *(int4v*)(Cs + row * 400 + ch * 16);
        }
        __syncthreads();   // Cs free for next rt
    }
}

// ---------------------------------------------------------------------------
// Kernel 3: persistent GRU. grid = 256 blocks x 512 thr (8 waves), 2 rows/block.
// Whh k[0,224) in VGPRs (wf[6][7]); k[224,256) in LDS at 72B stride
// (conflict-free). h as 2x512B in LDS, disjoint-bank swizzle (row1 XOR 64B).
// 2-deep A-read pipeline. NO setprio (A/B vs round 10: setprio hurts
// barrier-lockstep kernels per m190). One lgkm-only barrier per step.
// ---------------------------------------------------------------------------
__global__ __launch_bounds__(512) void k_gru(
    const uint16_t* __restrict__ XG, const float* __restrict__ Whh,
    const float* __restrict__ bhh, uint16_t* __restrict__ Y,
    float* __restrict__ hlast)
{
    constexpr int L = 128;
    __shared__ __align__(16) char Abuf[2][2 * 512];   // h bf16, 2 rows, swizzled
    __shared__ __align__(16) char Wt[768 * 72 + 8];   // Whh k-tail [224,256), 72B stride
    const int tid = threadIdx.x;
    const int w = tid >> 6, l = tid & 63, lr = l & 15, lg = l >> 4;
    const int rowg0 = blockIdx.x * 2;

    ((uint32_t*)Abuf)[tid] = 0;                        // zero both h buffers (512 words)

    #pragma unroll
    for (int it = 0; it < 6; ++it) {                   // stage Wt: 768 rows x 4 chunks
        int c = it * 512 + tid; int r = c >> 2, cc = c & 3;
        bf16x8 v = cvt8(Whh + (long)r * 256 + 224 + cc * 8);
        *(int4v*)(Wt + r * 72 + cc * 16) = asint4(v);
    }

    int gb[6];
    #pragma unroll
    for (int tl = 0; tl < 6; ++tl) gb[tl] = (tl >> 1) * 256 + w * 32 + (tl & 1) * 16;
    bf16x8 wf[6][7];                                   // K 0..223 register-resident
    #pragma unroll
    for (int tl = 0; tl < 6; ++tl)
        #pragma unroll
        for (int ks = 0; ks < 7; ++ks)
            wf[tl][ks] = cvt8(Whh + (long)(gb[tl] + lr) * 256 + ks * 32 + lg * 8);

    const int i_  = lg & 1;                            // local batch row 0/1
    const int sub = (lg >> 1) & 1;
    const int col = w * 32 + sub * 16 + lr;            // h column 0..255
    const float bR = bhh[col], bZ = bhh[256 + col], bN = bhh[512 + col];
    const long rowl = rowg0 + i_;                      // global batch row
    // disjoint-bank h layout: row i_ region at i_*512, chunk base XOR (i_<<6)
    const int wrbyte = i_ * 512 + ((((col * 2) & ~15) ^ (i_ << 6)) | ((col * 2) & 15));

    uint16_t xga0 = XG[rowl * 768 + col];              // xg(t=0) prefetch
    uint16_t xga1 = XG[rowl * 768 + 256 + col];
    uint16_t xga2 = XG[rowl * 768 + 512 + col];
    float h = 0.f;
    const bool wy = (Y != nullptr);
    const int arow = lr & 1;                           // broadcast A row
    __syncthreads();

    for (int t = 0; t < L; ++t) {
        const int p = t & 1;
        f32x4 acc[6];
        #pragma unroll
        for (int i = 0; i < 6; ++i) acc[i] = (f32x4){0.f, 0.f, 0.f, 0.f};

        const char* ab = Abuf[p];
        bf16x8 acur = *(bf16x8*)(ab + arow * 512 + ((lg * 16) ^ (arow << 6)));
        #pragma unroll
        for (int ks = 0; ks < 8; ++ks) {
            bf16x8 anx;
            if (ks < 7)
                anx = *(bf16x8*)(ab + arow * 512 + (((ks + 1) * 64 + lg * 16) ^ (arow << 6)));
            if (ks < 7) {
                #pragma unroll
                for (int tl = 0; tl < 6; ++tl) acc[tl] = mfma16(acur, wf[tl][ks], acc[tl]);
            } else {
                #pragma unroll
                for (int tl = 0; tl < 6; ++tl) {
                    bf16x8 b = *(bf16x8*)(Wt + (gb[tl] + lr) * 72 + lg * 16);
                    acc[tl] = mfma16(acur, b, acc[tl]);
                }
            }
            acur = anx;
        }

        float pre0, pre1, pre2;
        {
            float a0 = i_ ? acc[0][1] : acc[0][0];
            float a1 = i_ ? acc[1][1] : acc[1][0];
            pre0 = sub ? a1 : a0;
            float b0 = i_ ? acc[2][1] : acc[2][0];
            float b1 = i_ ? acc[3][1] : acc[3][0];
            pre1 = sub ? b1 : b0;
            float c0 = i_ ? acc[4][1] : acc[4][0];
            float c1 = i_ ? acc[5][1] : acc[5][0];
            pre2 = sub ? c1 : c0;
        }
        float xr = bf2f(xga0), xz = bf2f(xga1), xn = bf2f(xga2);
        float R = sigm(xr + pre0 + bR);
        float Z = sigm(xz + pre1 + bZ);
        float N = tanhfast(xn + R * (pre2 + bN));
        h = N + Z * (h - N);
        uint16_t hb = f2bf(h);
        *(uint16_t*)(Abuf[p ^ 1] + wrbyte) = hb;

        if (t + 1 < L) {                               // prefetch xg(t+1)
            const uint16_t* src = XG + ((long)(t + 1) * 512 + rowl) * 768;
            xga0 = src[col]; xga1 = src[256 + col]; xga2 = src[512 + col];
        }
        if (wy) Y[((long)t * 512 + rowl) * 256 + col] = hb;
        bar_lds();
    }
    if (hlast) hlast[rowl * 256 + col] = h;
}

// ---------------------------------------------------------------------------
// Kernel 4: mu / log_var / z.  grid = 256 blocks x 256 thr, 2 rows/block.
// ---------------------------------------------------------------------------
__global__ __launch_bounds__(256) void k_z(
    const float* __restrict__ hlast, const float* __restrict__ muW,
    const float* __restrict__ mub, const float* __restrict__ lvW,
    const float* __restrict__ lvb, const float* __restrict__ eps,
    float* __restrict__ mu_out, float* __restrict__ lv_out,
    float* __restrict__ zout)
{
    __shared__ float hrow[2][256];
    __shared__ float res[2][128];
    const int tid = threadIdx.x;
    const long row0 = (long)blockIdx.x * 2;
    for (int i = tid; i < 512; i += 256) ((float*)hrow)[i] = hlast[row0 * 256 + i];
    __syncthreads();
    const int lrr = tid >> 7, c = tid & 127;
    const float* Wr = (c < 64 ? muW : lvW) + (long)(c & 63) * 256;
    float acc = (c < 64) ? mub[c] : lvb[c & 63];
    const float* hr = hrow[lrr];
    #pragma unroll 8
    for (int k = 0; k < 256; k += 4) {
        f32x4 wv = *(const f32x4*)(Wr + k);
        #pragma unroll
        for (int e = 0; e < 4; ++e) acc += hr[k + e] * wv[e];
    }
    res[lrr][c] = acc;
    long row = row0 + lrr;
    if (c < 64) mu_out[row * 64 + c] = acc;
    else        lv_out[row * 64 + (c & 63)] = acc;
    __syncthreads();
    if (c < 64) {
        float m = res[lrr][c], lv = res[lrr][64 + c];
        zout[row * 64 + c] = m + eps[row * 64 + c] * __expf(0.5f * lv);
    }
}

// ---------------------------------------------------------------------------
// Kernel 5: post proj + ReLU + LN, then output proj + tanh -> x_hat (f32).
// D1 rows are t-major ri; x_hat written b-major. grid 1024 x 256 thr.
// ---------------------------------------------------------------------------
__global__ __launch_bounds__(256) void k_post(
    const uint16_t* __restrict__ D1, const float* __restrict__ pW,
    const float* __restrict__ pb, const float* __restrict__ pg,
    const float* __restrict__ pbeta, const float* __restrict__ oW,
    const float* __restrict__ ob, float* __restrict__ xhat)
{
    __shared__ __align__(16) char Bs[256 * 512];
    const int tid = threadIdx.x;
    const long rowbase = (long)blockIdx.x * 64;
    #pragma unroll
    for (int it = 0; it < 32; ++it) {
        int c = it * 256 + tid; int r = c >> 5, cc = c & 31;
        bf16x8 v = cvt8(pW + r * 256 + cc * 8);
        *(int4v*)(Bs + r * 512 + ((cc * 16) ^ ((r & 7) << 4))) = asint4(v);
    }
    __syncthreads();
    const int w = tid >> 6, l = tid & 63, lr = l & 15, lg = l >> 4;
    const long arow = rowbase + w * 16 + lr;
    bf16x8 af[8];
    #pragma unroll
    for (int ks = 0; ks < 8; ++ks) af[ks] = *(const bf16x8*)(D1 + arow * 256 + ks * 32 + lg * 8);
    f32x4 acc[16];
    #pragma unroll
    for (int i = 0; i < 16; ++i) acc[i] = (f32x4){0.f, 0.f, 0.f, 0.f};
    #pragma unroll
    for (int ks = 0; ks < 8; ++ks) {
        #pragma unroll
        for (int tl = 0; tl < 16; ++tl) {
            int n = tl * 16 + lr;
            bf16x8 b = *(bf16x8*)(Bs + n * 512 + ((ks * 64 + lg * 16) ^ ((n & 7) << 4)));
            acc[tl] = mfma16(af[ks], b, acc[tl]);
        }
    }
    float gv[16], bv[16], biasv[16];
    #pragma unroll
    for (int tl = 0; tl < 16; ++tl) {
        int col = tl * 16 + lr;
        gv[tl] = pg[col]; bv[tl] = pbeta[col]; biasv[tl] = pb[col];
    }
    uint16_t dl[16][4];
    #pragma unroll
    for (int i = 0; i < 4; ++i) {
        float s = 0.f, sq = 0.f, v[16];
        #pragma unroll
        for (int tl = 0; tl < 16; ++tl) {
            float xv = acc[tl][i] + biasv[tl]; xv = fmaxf(xv, 0.f);
            v[tl] = xv; s += xv; sq += xv * xv;
        }
        #pragma unroll
        for (int d = 1; d < 16; d <<= 1) { s += __shfl_xor(s, d); sq += __shfl_xor(sq, d); }
        float mean = s * (1.f / 256.f);
        float var  = sq * (1.f / 256.f) - mean * mean;
        float sc   = rsqrtf(var + 1e-5f);
        #pragma unroll
        for (int tl = 0; tl < 16; ++tl)
            dl[tl][i] = f2bf((v[tl] - mean) * sc * gv[tl] + bv[tl]);
    }
    __syncthreads();
    #pragma unroll
    for (int tl = 0; tl < 16; ++tl) {
        int col = tl * 16 + lr;
        #pragma unroll
        for (int i = 0; i < 4; ++i) {
            int row = w * 16 + lg * 4 + i;
            *(uint16_t*)(Bs + row * 512 + (((col * 2) & ~15) ^ ((row & 7) << 4)) + ((col * 2) & 15)) = dl[tl][i];
        }
    }
    __syncthreads();
    const int ar2 = w * 16 + lr;
    f32x4 acc2[4];
    #pragma unroll
    for (int i = 0; i < 4; ++i) acc2[i] = (f32x4){0.f, 0.f, 0.f, 0.f};
    #pragma unroll
    for (int ks = 0; ks < 8; ++ks) {
        bf16x8 a = *(bf16x8*)(Bs + ar2 * 512 + ((ks * 64 + lg * 16) ^ ((ar2 & 7) << 4)));
        #pragma unroll
        for (int tl = 0; tl < 4; ++tl) {
            int n = tl * 16 + lr;
            bf16x8 b = cvt8(oW + n * 256 + ks * 32 + lg * 8);
            acc2[tl] = mfma16(a, b, acc2[tl]);
        }
    }
    #pragma unroll
    for (int tl = 0; tl < 4; ++tl) {
        int col = tl * 16 + lr;
        float bo = ob[col];
        #pragma unroll
        for (int i = 0; i < 4; ++i) {
            long ri = rowbase + w * 16 + lg * 4 + i;
            long b = ri & 511, t = ri >> 9;
            xhat[(b * 128 + t) * 64 + col] = tanhfast(acc2[tl][i] + bo);
        }
    }
}

// ---------------------------------------------------------------------------
extern "C" void kernel_launch(void* const* d_in, const int* in_sizes, int n_in,
                              void* d_out, int out_size, void* d_ws, size_t ws_size,
                              hipStream_t stream)
{
    (void)in_sizes; (void)n_in; (void)out_size; (void)ws_size;
    const float* x     = (const float*)d_in[0];
    const float* eps   = (const float*)d_in[1];
    const float* dnz   = (const float*)d_in[2];
    const float* in_W  = (const float*)d_in[3];
    const float* in_b  = (const float*)d_in[4];
    const float* in_g  = (const float*)d_in[5];
    const float* in_be = (const float*)d_in[6];
    const float* eW0i  = (const float*)d_in[7];
    const float* eW0h  = (const float*)d_in[8];
    const float* eb0i  = (const float*)d_in[9];
    const float* eb0h  = (const float*)d_in[10];
    const float* eW1i  = (const float*)d_in[11];
    const float* eW1h  = (const float*)d_in[12];
    const float* eb1i  = (const float*)d_in[13];
    const float* eb1h  = (const float*)d_in[14];
    const float* mu_W  = (const float*)d_in[15];
    const float* mu_b  = (const float*)d_in[16];
    const float* lv_W  = (const float*)d_in[17];
    const float* lv_b  = (const float*)d_in[18];
    const float* dW0i  = (const float*)d_in[19];
    const float* dW0h  = (const float*)d_in[20];
    const float* db0i  = (const float*)d_in[21];
    const float* db0h  = (const float*)d_in[22];
    const float* dW1i  = (const float*)d_in[23];
    const float* dW1h  = (const float*)d_in[24];
    const float* db1i  = (const float*)d_in[25];
    const float* db1h  = (const float*)d_in[26];
    const float* postW = (const float*)d_in[27];
    const float* postb = (const float*)d_in[28];
    const float* postg = (const float*)d_in[29];
    const float* postbe= (const float*)d_in[30];
    const float* outW  = (const float*)d_in[31];
    const float* outb  = (const float*)d_in[32];

    char* ws = (char*)d_ws;
    uint16_t* XG   = (uint16_t*)(ws);                 // 65536*768*2 = 100663296 B
    uint16_t* YA   = (uint16_t*)(ws + 100663296);     // 33554432 B
    uint16_t* YB   = (uint16_t*)(ws + 134217728);     // 33554432 B
    float*    hlast= (float*)   (ws + 167772160);     // 524288 B
    float*    zbuf = (float*)   (ws + 168296448);     // 131072 B

    float* out    = (float*)d_out;
    float* mu_out = out + 4194304;
    float* lv_out = out + 4194304 + 32768;

    dim3 b256(256), b512(512);
    dim3 gxg(64, 4);

    k_inproj<<<1024, b256, 0, stream>>>(x, in_W, in_b, in_g, in_be, YA);
    k_xg<256,false><<<gxg, b512, 0, stream>>>(YA, eW0i, eb0i, XG, nullptr, nullptr);
    k_gru<<<256, b512, 0, stream>>>(XG, eW0h, eb0h, YB, nullptr);
    k_xg<256,false><<<gxg, b512, 0, stream>>>(YB, eW1i, eb1i, XG, nullptr, nullptr);
    k_gru<<<256, b512, 0, stream>>>(XG, eW1h, eb1h, nullptr, hlast);
    k_z<<<256, b256, 0, stream>>>(hlast, mu_W, mu_b, lv_W, lv_b, eps, mu_out, lv_out, zbuf);
    k_xg<64,true><<<gxg, b512, 0, stream>>>(nullptr, dW0i, db0i, XG, zbuf, dnz);
    k_gru<<<256, b512, 0, stream>>>(XG, dW0h, db0h, YA, nullptr);
    k_xg<256,false><<<gxg, b512, 0, stream>>>(YA, dW1i, db1i, XG, nullptr, nullptr);
    k_gru<<<256, b512, 0, stream>>>(XG, dW1h, db1h, YB, nullptr);
    k_post<<<1024, b256, 0, stream>>>(YB, postW, postb, postg, postbe, outW, outb, out);
}

// Round 13
// 955.105 us; speedup vs baseline: 1.0887x; 1.0028x over previous
//
#include <hip/hip_runtime.h>
#include <hip/hip_bf16.h>
#include <stdint.h>

#define DEVI static __device__ __forceinline__

typedef __bf16 bf16x8 __attribute__((ext_vector_type(8)));
typedef float f32x4 __attribute__((ext_vector_type(4)));
typedef int   int4v __attribute__((ext_vector_type(4)));
typedef int   int2v __attribute__((ext_vector_type(2)));

DEVI float bf2f(uint16_t u){ uint32_t x = ((uint32_t)u) << 16; float f; __builtin_memcpy(&f, &x, 4); return f; }
DEVI uint16_t f2bf(float f){ uint32_t u; __builtin_memcpy(&u, &f, 4); uint32_t r = (u + 0x7FFFu + ((u >> 16) & 1u)) >> 16; return (uint16_t)r; }
DEVI float frcp(float x){ return __builtin_amdgcn_rcpf(x); }
DEVI float sigm(float x){ return frcp(1.f + __expf(-x)); }
DEVI float tanhfast(float x){ return 1.f - 2.f * frcp(1.f + __expf(2.f * x)); }
DEVI f32x4 mfma16(bf16x8 a, bf16x8 b, f32x4 c){ return __builtin_amdgcn_mfma_f32_16x16x32_bf16(a, b, c, 0, 0, 0); }

DEVI bf16x8 cvt8(const float* __restrict__ p){
    f32x4 a = *(const f32x4*)p, b = *(const f32x4*)(p + 4);
    union { bf16x8 v; uint16_t u[8]; } r;
    #pragma unroll
    for (int e = 0; e < 4; ++e) { r.u[e] = f2bf(a[e]); r.u[4 + e] = f2bf(b[e]); }
    return r.v;
}
DEVI int4v asint4(bf16x8 v){ int4v r; __builtin_memcpy(&r, &v, 16); return r; }

// raw barrier: lgkm drain only (vm ops — prefetch loads / Y stores — stay in flight)
DEVI void bar_lds(){
    asm volatile("s_waitcnt lgkmcnt(0)" ::: "memory");
    __builtin_amdgcn_s_barrier();
    __builtin_amdgcn_sched_barrier(0);
}

// XG layout (row-major, t-major rows): element (t, b, c) at (t*512 + b)*768 + c.

// ---------------------------------------------------------------------------
// Kernel 1: input projection (B*L,64)@(64,256) + bias + ReLU + LN -> Y bf16
// Y rows in t-major order: ri = t*512 + b. LDS-staged coalesced Y writes.
// grid 1024 x 256 thr.
// ---------------------------------------------------------------------------
__global__ __launch_bounds__(256) void k_inproj(
    const float* __restrict__ X, const float* __restrict__ W,
    const float* __restrict__ bias, const float* __restrict__ g,
    const float* __restrict__ beta, uint16_t* __restrict__ Y)
{
    __shared__ __align__(16) char As[64 * 128];
    __shared__ __align__(16) char Bs[256 * 128];
    __shared__ __align__(16) char Cs[64 * 520];   // staging, 520B stride (conflict-free)
    const int tid = threadIdx.x;
    const long rowbase = (long)blockIdx.x * 64;

    #pragma unroll
    for (int it = 0; it < 2; ++it) {
        int c = it * 256 + tid; int r = c >> 3, cc = c & 7;
        bf16x8 v = cvt8(X + (rowbase + r) * 64 + cc * 8);
        *(int4v*)(As + r * 128 + ((cc * 16) ^ ((r & 7) << 4))) = asint4(v);
    }
    #pragma unroll
    for (int it = 0; it < 8; ++it) {
        int c = it * 256 + tid; int r = c >> 3, cc = c & 7;
        bf16x8 v = cvt8(W + r * 64 + cc * 8);
        *(int4v*)(Bs + r * 128 + ((cc * 16) ^ ((r & 7) << 4))) = asint4(v);
    }
    __syncthreads();

    const int w = tid >> 6, l = tid & 63, lr = l & 15, lg = l >> 4;
    f32x4 acc[16];
    #pragma unroll
    for (int i = 0; i < 16; ++i) acc[i] = (f32x4){0.f, 0.f, 0.f, 0.f};
    const int arow = w * 16 + lr;
    #pragma unroll
    for (int ks = 0; ks < 2; ++ks) {
        bf16x8 a = *(bf16x8*)(As + arow * 128 + ((ks * 64 + lg * 16) ^ ((arow & 7) << 4)));
        #pragma unroll
        for (int tl = 0; tl < 16; ++tl) {
            int n = tl * 16 + lr;
            bf16x8 b = *(bf16x8*)(Bs + n * 128 + ((ks * 64 + lg * 16) ^ ((n & 7) << 4)));
            acc[tl] = mfma16(a, b, acc[tl]);
        }
    }
    float gv[16], bv[16], biasv[16];
    #pragma unroll
    for (int tl = 0; tl < 16; ++tl) {
        int col = tl * 16 + lr;
        gv[tl] = g[col]; bv[tl] = beta[col]; biasv[tl] = bias[col];
    }
    #pragma unroll
    for (int i = 0; i < 4; ++i) {
        float s = 0.f, sq = 0.f, v[16];
        #pragma unroll
        for (int tl = 0; tl < 16; ++tl) {
            float xv = acc[tl][i] + biasv[tl]; xv = fmaxf(xv, 0.f);
            v[tl] = xv; s += xv; sq += xv * xv;
        }
        #pragma unroll
        for (int d = 1; d < 16; d <<= 1) { s += __shfl_xor(s, d); sq += __shfl_xor(sq, d); }
        float mean = s * (1.f / 256.f);
        float var  = sq * (1.f / 256.f) - mean * mean;
        float sc   = rsqrtf(var + 1e-5f);
        int rl = w * 16 + lg * 4 + i;
        #pragma unroll
        for (int tl = 0; tl < 16; ++tl)
            *(uint16_t*)(Cs + rl * 520 + (tl * 16 + lr) * 2) =
                f2bf((v[tl] - mean) * sc * gv[tl] + bv[tl]);
    }
    __syncthreads();
    #pragma unroll
    for (int it = 0; it < 16; ++it) {
        int idx = it * 256 + tid;
        int rl = idx >> 6, ch = idx & 63;
        long rg = rowbase + rl;
        long ri = ((rg & 127) << 9) + (rg >> 7);      // t-major
        *(int2v*)(Y + ri * 256 + ch * 4) = *(int2v*)(Cs + rl * 520 + ch * 8);
    }
}

// ---------------------------------------------------------------------------
// Kernel 2: input-gate GEMM, persistent-N. Block owns a 192-col strip (B in
// LDS once), loops 8 x 128-row tiles; A-frags loaded global->reg per tile.
// Output tile staged in LDS (400B row stride), then written as contiguous
// 16B/lane dwordx4 spans — eliminates partial-sector RMW on XG stores.
// grid (64, 4) x 512 thr.
// ---------------------------------------------------------------------------
template<int KIN, bool ZBUILD>
__global__ __launch_bounds__(512) void k_xg(
    const uint16_t* __restrict__ A, const float* __restrict__ W,
    const float* __restrict__ bias, uint16_t* __restrict__ XG,
    const float* __restrict__ zbuf, const float* __restrict__ noise)
{
    constexpr int KB = KIN * 2;           // bf16 row bytes
    constexpr int KS = KIN / 32;          // mfma k-steps
    __shared__ __align__(16) char Bs[192 * KB];
    __shared__ __align__(16) char Cs[128 * 400];   // out-tile staging
    const int tid = threadIdx.x;
    const int nb = blockIdx.y;

    constexpr int CPR = KIN / 8;          // 8-f32 chunks per row
    for (int c = tid; c < 192 * CPR; c += 512) {
        int r = c / CPR, cc = c % CPR;
        bf16x8 v = cvt8(W + (long)(nb * 192 + r) * KIN + cc * 8);
        *(int4v*)(Bs + r * KB + ((cc * 16) ^ ((r & 7) << 4))) = asint4(v);
    }
    __syncthreads();

    const int w = tid >> 6, l = tid & 63, lr = l & 15, lg = l >> 4;
    float bvs[12];
    #pragma unroll
    for (int tl = 0; tl < 12; ++tl) bvs[tl] = bias[nb * 192 + tl * 16 + lr];

    for (int rt = 0; rt < 8; ++rt) {
        const long rowb = (long)blockIdx.x * 1024 + rt * 128;
        const long ria  = rowb + w * 16 + lr;
        bf16x8 a[KS];
        if constexpr (!ZBUILD) {
            #pragma unroll
            for (int ks = 0; ks < KS; ++ks)
                a[ks] = *(const bf16x8*)(A + ria * KIN + ks * 32 + lg * 8);
        } else {
            int b = (int)(ria & 511), t = (int)(ria >> 9);
            #pragma unroll
            for (int ks = 0; ks < KS; ++ks) {
                int k0 = ks * 32 + lg * 8;
                const float* zr = zbuf + b * 64 + k0;
                const float* nr = noise + ((long)b * 128 + t) * 64 + k0;
                f32x4 z0 = *(const f32x4*)zr, z1 = *(const f32x4*)(zr + 4);
                f32x4 n0 = *(const f32x4*)nr, n1 = *(const f32x4*)(nr + 4);
                union { bf16x8 v; uint16_t u[8]; } un;
                #pragma unroll
                for (int e = 0; e < 4; ++e) {
                    un.u[e]     = f2bf(z0[e] + 0.05f * n0[e]);
                    un.u[4 + e] = f2bf(z1[e] + 0.05f * n1[e]);
                }
                a[ks] = un.v;
            }
        }
        f32x4 acc[12];
        #pragma unroll
        for (int i = 0; i < 12; ++i) acc[i] = (f32x4){0.f, 0.f, 0.f, 0.f};
        #pragma unroll
        for (int ks = 0; ks < KS; ++ks) {
            #pragma unroll
            for (int tl = 0; tl < 12; ++tl) {
                int n = tl * 16 + lr;
                bf16x8 b = *(bf16x8*)(Bs + n * KB + ((ks * 64 + lg * 16) ^ ((n & 7) << 4)));
                acc[tl] = mfma16(a[ks], b, acc[tl]);
            }
        }
        // stage output tile in LDS: row = w*16+lg*4+i (0..127), col = tl*16+lr
        #pragma unroll
        for (int tl = 0; tl < 12; ++tl) {
            #pragma unroll
            for (int i = 0; i < 4; ++i)
                *(uint16_t*)(Cs + (w * 16 + lg * 4 + i) * 400 + (tl * 16 + lr) * 2) =
                    f2bf(acc[tl][i] + bvs[tl]);
        }
        __syncthreads();
        // write out: 128 rows x 384B strip, 16B/lane contiguous (3072 chunks)
        #pragma unroll
        for (int it = 0; it < 6; ++it) {
            int idx = it * 512 + tid;
            int row = idx / 24, ch = idx % 24;
            *(int4v*)(XG + (rowb + row) * 768 + nb * 192 + ch * 8) =
                *(int4v*)(Cs + row * 400 + ch * 16);
        }
        __syncthreads();   // Cs free for next rt
    }
}

// ---------------------------------------------------------------------------
// Kernel 3: persistent GRU. grid = 256 blocks x 512 thr (8 waves), 2 rows/block.
// Whh k[0,224) in VGPRs (wf[6][7]); k[224,256) in LDS at 72B stride
// (conflict-free). h as 2x512B in LDS, disjoint-bank swizzle (row1 XOR 64B).
// 4-deep circular A-frag prefetch (aq[4], static idx after full unroll):
// ~120cyc lookahead covers ds_read latency (2-deep gave only ~30cyc).
// No setprio (hurts lockstep waves, r12 A/B). One lgkm barrier per step.
// ---------------------------------------------------------------------------
__global__ __launch_bounds__(512) void k_gru(
    const uint16_t* __restrict__ XG, const float* __restrict__ Whh,
    const float* __restrict__ bhh, uint16_t* __restrict__ Y,
    float* __restrict__ hlast)
{
    constexpr int L = 128;
    __shared__ __align__(16) char Abuf[2][2 * 512];   // h bf16, 2 rows, swizzled
    __shared__ __align__(16) char Wt[768 * 72 + 8];   // Whh k-tail [224,256), 72B stride
    const int tid = threadIdx.x;
    const int w = tid >> 6, l = tid & 63, lr = l & 15, lg = l >> 4;
    const int rowg0 = blockIdx.x * 2;

    ((uint32_t*)Abuf)[tid] = 0;                        // zero both h buffers (512 words)

    #pragma unroll
    for (int it = 0; it < 6; ++it) {                   // stage Wt: 768 rows x 4 chunks
        int c = it * 512 + tid; int r = c >> 2, cc = c & 3;
        bf16x8 v = cvt8(Whh + (long)r * 256 + 224 + cc * 8);
        *(int4v*)(Wt + r * 72 + cc * 16) = asint4(v);
    }

    int gb[6];
    #pragma unroll
    for (int tl = 0; tl < 6; ++tl) gb[tl] = (tl >> 1) * 256 + w * 32 + (tl & 1) * 16;
    bf16x8 wf[6][7];                                   // K 0..223 register-resident
    #pragma unroll
    for (int tl = 0; tl < 6; ++tl)
        #pragma unroll
        for (int ks = 0; ks < 7; ++ks)
            wf[tl][ks] = cvt8(Whh + (long)(gb[tl] + lr) * 256 + ks * 32 + lg * 8);

    const int i_  = lg & 1;                            // local batch row 0/1
    const int sub = (lg >> 1) & 1;
    const int col = w * 32 + sub * 16 + lr;            // h column 0..255
    const float bR = bhh[col], bZ = bhh[256 + col], bN = bhh[512 + col];
    const long rowl = rowg0 + i_;                      // global batch row
    // disjoint-bank h layout: row i_ region at i_*512, chunk base XOR (i_<<6)
    const int wrbyte = i_ * 512 + ((((col * 2) & ~15) ^ (i_ << 6)) | ((col * 2) & 15));

    uint16_t xga0 = XG[rowl * 768 + col];              // xg(t=0) prefetch
    uint16_t xga1 = XG[rowl * 768 + 256 + col];
    uint16_t xga2 = XG[rowl * 768 + 512 + col];
    float h = 0.f;
    const bool wy = (Y != nullptr);
    const int arow = lr & 1;                           // broadcast A row
    __syncthreads();

    for (int t = 0; t < L; ++t) {
        const int p = t & 1;
        f32x4 acc[6];
        #pragma unroll
        for (int i = 0; i < 6; ++i) acc[i] = (f32x4){0.f, 0.f, 0.f, 0.f};

        const char* ab = Abuf[p];
        // 4-deep circular A-frag prefetch (indices static after full unroll)
        bf16x8 aq[4];
        #pragma unroll
        for (int i = 0; i < 4; ++i)
            aq[i] = *(bf16x8*)(ab + arow * 512 + ((i * 64 + lg * 16) ^ (arow << 6)));
        #pragma unroll
        for (int ks = 0; ks < 8; ++ks) {
            bf16x8 acur = aq[ks & 3];
            if (ks + 4 < 8)
                aq[ks & 3] = *(bf16x8*)(ab + arow * 512 + (((ks + 4) * 64 + lg * 16) ^ (arow << 6)));
            if (ks < 7) {
                #pragma unroll
                for (int tl = 0; tl < 6; ++tl) acc[tl] = mfma16(acur, wf[tl][ks], acc[tl]);
            } else {
                #pragma unroll
                for (int tl = 0; tl < 6; ++tl) {
                    bf16x8 b = *(bf16x8*)(Wt + (gb[tl] + lr) * 72 + lg * 16);
                    acc[tl] = mfma16(acur, b, acc[tl]);
                }
            }
        }

        float pre0, pre1, pre2;
        {
            float a0 = i_ ? acc[0][1] : acc[0][0];
            float a1 = i_ ? acc[1][1] : acc[1][0];
            pre0 = sub ? a1 : a0;
            float b0 = i_ ? acc[2][1] : acc[2][0];
            float b1 = i_ ? acc[3][1] : acc[3][0];
            pre1 = sub ? b1 : b0;
            float c0 = i_ ? acc[4][1] : acc[4][0];
            float c1 = i_ ? acc[5][1] : acc[5][0];
            pre2 = sub ? c1 : c0;
        }
        float xr = bf2f(xga0), xz = bf2f(xga1), xn = bf2f(xga2);
        float R = sigm(xr + pre0 + bR);
        float Z = sigm(xz + pre1 + bZ);
        float N = tanhfast(xn + R * (pre2 + bN));
        h = N + Z * (h - N);
        uint16_t hb = f2bf(h);
        *(uint16_t*)(Abuf[p ^ 1] + wrbyte) = hb;

        if (t + 1 < L) {                               // prefetch xg(t+1)
            const uint16_t* src = XG + ((long)(t + 1) * 512 + rowl) * 768;
            xga0 = src[col]; xga1 = src[256 + col]; xga2 = src[512 + col];
        }
        if (wy) Y[((long)t * 512 + rowl) * 256 + col] = hb;
        bar_lds();
    }
    if (hlast) hlast[rowl * 256 + col] = h;
}

// ---------------------------------------------------------------------------
// Kernel 4: mu / log_var / z.  grid = 256 blocks x 256 thr, 2 rows/block.
// ---------------------------------------------------------------------------
__global__ __launch_bounds__(256) void k_z(
    const float* __restrict__ hlast, const float* __restrict__ muW,
    const float* __restrict__ mub, const float* __restrict__ lvW,
    const float* __restrict__ lvb, const float* __restrict__ eps,
    float* __restrict__ mu_out, float* __restrict__ lv_out,
    float* __restrict__ zout)
{
    __shared__ float hrow[2][256];
    __shared__ float res[2][128];
    const int tid = threadIdx.x;
    const long row0 = (long)blockIdx.x * 2;
    for (int i = tid; i < 512; i += 256) ((float*)hrow)[i] = hlast[row0 * 256 + i];
    __syncthreads();
    const int lrr = tid >> 7, c = tid & 127;
    const float* Wr = (c < 64 ? muW : lvW) + (long)(c & 63) * 256;
    float acc = (c < 64) ? mub[c] : lvb[c & 63];
    const float* hr = hrow[lrr];
    #pragma unroll 8
    for (int k = 0; k < 256; k += 4) {
        f32x4 wv = *(const f32x4*)(Wr + k);
        #pragma unroll
        for (int e = 0; e < 4; ++e) acc += hr[k + e] * wv[e];
    }
    res[lrr][c] = acc;
    long row = row0 + lrr;
    if (c < 64) mu_out[row * 64 + c] = acc;
    else        lv_out[row * 64 + (c & 63)] = acc;
    __syncthreads();
    if (c < 64) {
        float m = res[lrr][c], lv = res[lrr][64 + c];
        zout[row * 64 + c] = m + eps[row * 64 + c] * __expf(0.5f * lv);
    }
}

// ---------------------------------------------------------------------------
// Kernel 5: post proj + ReLU + LN, then output proj + tanh -> x_hat (f32).
// D1 rows are t-major ri; x_hat written b-major. grid 1024 x 256 thr.
// ---------------------------------------------------------------------------
__global__ __launch_bounds__(256) void k_post(
    const uint16_t* __restrict__ D1, const float* __restrict__ pW,
    const float* __restrict__ pb, const float* __restrict__ pg,
    const float* __restrict__ pbeta, const float* __restrict__ oW,
    const float* __restrict__ ob, float* __restrict__ xhat)
{
    __shared__ __align__(16) char Bs[256 * 512];
    const int tid = threadIdx.x;
    const long rowbase = (long)blockIdx.x * 64;
    #pragma unroll
    for (int it = 0; it < 32; ++it) {
        int c = it * 256 + tid; int r = c >> 5, cc = c & 31;
        bf16x8 v = cvt8(pW + r * 256 + cc * 8);
        *(int4v*)(Bs + r * 512 + ((cc * 16) ^ ((r & 7) << 4))) = asint4(v);
    }
    __syncthreads();
    const int w = tid >> 6, l = tid & 63, lr = l & 15, lg = l >> 4;
    const long arow = rowbase + w * 16 + lr;
    bf16x8 af[8];
    #pragma unroll
    for (int ks = 0; ks < 8; ++ks) af[ks] = *(const bf16x8*)(D1 + arow * 256 + ks * 32 + lg * 8);
    f32x4 acc[16];
    #pragma unroll
    for (int i = 0; i < 16; ++i) acc[i] = (f32x4){0.f, 0.f, 0.f, 0.f};
    #pragma unroll
    for (int ks = 0; ks < 8; ++ks) {
        #pragma unroll
        for (int tl = 0; tl < 16; ++tl) {
            int n = tl * 16 + lr;
            bf16x8 b = *(bf16x8*)(Bs + n * 512 + ((ks * 64 + lg * 16) ^ ((n & 7) << 4)));
            acc[tl] = mfma16(af[ks], b, acc[tl]);
        }
    }
    float gv[16], bv[16], biasv[16];
    #pragma unroll
    for (int tl = 0; tl < 16; ++tl) {
        int col = tl * 16 + lr;
        gv[tl] = pg[col]; bv[tl] = pbeta[col]; biasv[tl] = pb[col];
    }
    uint16_t dl[16][4];
    #pragma unroll
    for (int i = 0; i < 4; ++i) {
        float s = 0.f, sq = 0.f, v[16];
        #pragma unroll
        for (int tl = 0; tl < 16; ++tl) {
            float xv = acc[tl][i] + biasv[tl]; xv = fmaxf(xv, 0.f);
            v[tl] = xv; s += xv; sq += xv * xv;
        }
        #pragma unroll
        for (int d = 1; d < 16; d <<= 1) { s += __shfl_xor(s, d); sq += __shfl_xor(sq, d); }
        float mean = s * (1.f / 256.f);
        float var  = sq * (1.f / 256.f) - mean * mean;
        float sc   = rsqrtf(var + 1e-5f);
        #pragma unroll
        for (int tl = 0; tl < 16; ++tl)
            dl[tl][i] = f2bf((v[tl] - mean) * sc * gv[tl] + bv[tl]);
    }
    __syncthreads();
    #pragma unroll
    for (int tl = 0; tl < 16; ++tl) {
        int col = tl * 16 + lr;
        #pragma unroll
        for (int i = 0; i < 4; ++i) {
            int row = w * 16 + lg * 4 + i;
            *(uint16_t*)(Bs + row * 512 + (((col * 2) & ~15) ^ ((row & 7) << 4)) + ((col * 2) & 15)) = dl[tl][i];
        }
    }
    __syncthreads();
    const int ar2 = w * 16 + lr;
    f32x4 acc2[4];
    #pragma unroll
    for (int i = 0; i < 4; ++i) acc2[i] = (f32x4){0.f, 0.f, 0.f, 0.f};
    #pragma unroll
    for (int ks = 0; ks < 8; ++ks) {
        bf16x8 a = *(bf16x8*)(Bs + ar2 * 512 + ((ks * 64 + lg * 16) ^ ((ar2 & 7) << 4)));
        #pragma unroll
        for (int tl = 0; tl < 4; ++tl) {
            int n = tl * 16 + lr;
            bf16x8 b = cvt8(oW + n * 256 + ks * 32 + lg * 8);
            acc2[tl] = mfma16(a, b, acc2[tl]);
        }
    }
    #pragma unroll
    for (int tl = 0; tl < 4; ++tl) {
        int col = tl * 16 + lr;
        float bo = ob[col];
        #pragma unroll
        for (int i = 0; i < 4; ++i) {
            long ri = rowbase + w * 16 + lg * 4 + i;
            long b = ri & 511, t = ri >> 9;
            xhat[(b * 128 + t) * 64 + col] = tanhfast(acc2[tl][i] + bo);
        }
    }
}

// ---------------------------------------------------------------------------
extern "C" void kernel_launch(void* const* d_in, const int* in_sizes, int n_in,
                              void* d_out, int out_size, void* d_ws, size_t ws_size,
                              hipStream_t stream)
{
    (void)in_sizes; (void)n_in; (void)out_size; (void)ws_size;
    const float* x     = (const float*)d_in[0];
    const float* eps   = (const float*)d_in[1];
    const float* dnz   = (const float*)d_in[2];
    const float* in_W  = (const float*)d_in[3];
    const float* in_b  = (const float*)d_in[4];
    const float* in_g  = (const float*)d_in[5];
    const float* in_be = (const float*)d_in[6];
    const float* eW0i  = (const float*)d_in[7];
    const float* eW0h  = (const float*)d_in[8];
    const float* eb0i  = (const float*)d_in[9];
    const float* eb0h  = (const float*)d_in[10];
    const float* eW1i  = (const float*)d_in[11];
    const float* eW1h  = (const float*)d_in[12];
    const float* eb1i  = (const float*)d_in[13];
    const float* eb1h  = (const float*)d_in[14];
    const float* mu_W  = (const float*)d_in[15];
    const float* mu_b  = (const float*)d_in[16];
    const float* lv_W  = (const float*)d_in[17];
    const float* lv_b  = (const float*)d_in[18];
    const float* dW0i  = (const float*)d_in[19];
    const float* dW0h  = (const float*)d_in[20];
    const float* db0i  = (const float*)d_in[21];
    const float* db0h  = (const float*)d_in[22];
    const float* dW1i  = (const float*)d_in[23];
    const float* dW1h  = (const float*)d_in[24];
    const float* db1i  = (const float*)d_in[25];
    const float* db1h  = (const float*)d_in[26];
    const float* postW = (const float*)d_in[27];
    const float* postb = (const float*)d_in[28];
    const float* postg = (const float*)d_in[29];
    const float* postbe= (const float*)d_in[30];
    const float* outW  = (const float*)d_in[31];
    const float* outb  = (const float*)d_in[32];

    char* ws = (char*)d_ws;
    uint16_t* XG   = (uint16_t*)(ws);                 // 65536*768*2 = 100663296 B
    uint16_t* YA   = (uint16_t*)(ws + 100663296);     // 33554432 B
    uint16_t* YB   = (uint16_t*)(ws + 134217728);     // 33554432 B
    float*    hlast= (float*)   (ws + 167772160);     // 524288 B
    float*    zbuf = (float*)   (ws + 168296448);     // 131072 B

    float* out    = (float*)d_out;
    float* mu_out = out + 4194304;
    float* lv_out = out + 4194304 + 32768;

    dim3 b256(256), b512(512);
    dim3 gxg(64, 4);

    k_inproj<<<1024, b256, 0, stream>>>(x, in_W, in_b, in_g, in_be, YA);
    k_xg<256,false><<<gxg, b512, 0, stream>>>(YA, eW0i, eb0i, XG, nullptr, nullptr);
    k_gru<<<256, b512, 0, stream>>>(XG, eW0h, eb0h, YB, nullptr);
    k_xg<256,false><<<gxg, b512, 0, stream>>>(YB, eW1i, eb1i, XG, nullptr, nullptr);
    k_gru<<<256, b512, 0, stream>>>(XG, eW1h, eb1h, nullptr, hlast);
    k_z<<<256, b256, 0, stream>>>(hlast, mu_W, mu_b, lv_W, lv_b, eps, mu_out, lv_out, zbuf);
    k_xg<64,true><<<gxg, b512, 0, stream>>>(nullptr, dW0i, db0i, XG, zbuf, dnz);
    k_gru<<<256, b512, 0, stream>>>(XG, dW0h, db0h, YA, nullptr);
    k_xg<256,false><<<gxg, b512, 0, stream>>>(YA, dW1i, db1i, XG, nullptr, nullptr);
    k_gru<<<256, b512, 0, stream>>>(XG, dW1h, db1h, YB, nullptr);
    k_post<<<1024, b256, 0, stream>>>(YB, postW, postb, postg, postbe, outW, outb, out);
}